// Round 3
// baseline (746.505 us; speedup 1.0000x reference)
//
#include <hip/hip_runtime.h>
#include <math.h>

#define BN_EPS_F 1e-5f

// ---------------------------------------------------------------------------
// Layer 1: K=8 — memory-bound, one thread per 4 outputs.
// ---------------------------------------------------------------------------
__global__ __launch_bounds__(256)
void l1_kernel(const float* __restrict__ G, const float* __restrict__ W1,
               const float* __restrict__ bias, const float* __restrict__ gamma,
               const float* __restrict__ beta, const float* __restrict__ mean,
               const float* __restrict__ var, float* __restrict__ h1)
{
    const int m = blockIdx.x;
    const int t = threadIdx.x;
    if (t >= 250) return;
    const int n = 4 * t;

    float4 g0 = *(const float4*)(G + (size_t)m * 8 + 0);
    float4 g1 = *(const float4*)(G + (size_t)m * 8 + 4);

    float4 bi = *(const float4*)(bias + n);
    float4 ga = *(const float4*)(gamma + n);
    float4 be = *(const float4*)(beta + n);
    float4 mu = *(const float4*)(mean + n);
    float4 va = *(const float4*)(var + n);

    float4 out;
    float* op = &out.x;
    const float* bip = &bi.x; const float* gap = &ga.x; const float* bep = &be.x;
    const float* mup = &mu.x; const float* vap = &va.x;
#pragma unroll
    for (int j = 0; j < 4; ++j) {
        const float* w = W1 + (size_t)(n + j) * 8;
        float4 w0 = *(const float4*)(w + 0);
        float4 w1 = *(const float4*)(w + 4);
        float d = g0.x*w0.x + g0.y*w0.y + g0.z*w0.z + g0.w*w0.w
                + g1.x*w1.x + g1.y*w1.y + g1.z*w1.z + g1.w*w1.w;
        float s  = gap[j] * rsqrtf(vap[j] + BN_EPS_F);
        float t0 = fmaf(s, bip[j] - mup[j], bep[j]);
        op[j] = fmaxf(fmaf(s, d, t0), 0.f);
    }
    *(float4*)(h1 + (size_t)m * 1000 + n) = out;
}

// ---------------------------------------------------------------------------
// fp32 NT GEMM, 8x8 per-thread tile (LDS-BW optimized), BM=64, BN=64*NW,
// BK=32, THREADS=64*NW (NW waves, each wave owns a 64x64 output quadrant).
// Lane (tx,ty) in 8x8 grid; thread tile = rows ty*8..+7, cols w*64+tx*8..+7.
// Double-buffered LDS with register prefetch; straight-line staging (no
// lambdas -> no scratch demotion). MODE 0: BN+relu, 1: BN+sigmoid, 2: raw
// partial store to C + z*zstride (split-K).
// ---------------------------------------------------------------------------
template<int NW, int MODE>
__global__ __launch_bounds__(64*NW, 2)
void gemm_f32(const float* __restrict__ A, int K, int lda,
              const float* __restrict__ B, int N, int ldb, int kchunk,
              const float* __restrict__ bias, const float* __restrict__ gamma,
              const float* __restrict__ beta, const float* __restrict__ mean,
              const float* __restrict__ var,
              float* __restrict__ C, int ldc, size_t zstride)
{
    constexpr int BN      = 64 * NW;
    constexpr int THREADS = 64 * NW;
    constexpr int RPP     = THREADS / 8;   // staging rows per pass
    constexpr int PA      = 64 / RPP;      // A staging passes
    constexpr int PB      = BN / RPP;      // B staging passes (=8)

    __shared__ float As[2][32][68];
    __shared__ float Bs[2][32][BN + 4];

    const int tid  = threadIdx.x;
    const int w    = tid >> 6;
    const int lane = tid & 63;
    const int tx   = lane & 7;
    const int ty   = lane >> 3;
    const int m0   = blockIdx.y * 64;
    const int n0   = blockIdx.x * BN;
    const int z    = blockIdx.z;
    const int ks   = z * kchunk;
    const int ke   = min(K, ks + kchunk);
    const int nt   = (ke - ks + 31) >> 5;

    const int srow = tid >> 3;
    const int skq  = tid & 7;

    float4 sa[PA], sb[PB];
    const float4 zf4 = make_float4(0.f, 0.f, 0.f, 0.f);

    float acc[8][8];
#pragma unroll
    for (int i = 0; i < 8; ++i)
#pragma unroll
        for (int j = 0; j < 8; ++j) acc[i][j] = 0.f;

#define GLOAD(KT) do {                                                        \
    const int kg_ = (KT) + 4 * skq;                                           \
    const bool kv_ = kg_ < ke;                                                \
    _Pragma("unroll")                                                         \
    for (int i_ = 0; i_ < PA; ++i_) {                                         \
        sa[i_] = kv_ ? *(const float4*)(A + (size_t)(m0 + srow + i_*RPP)*lda  \
                                          + kg_) : zf4;                       \
    }                                                                         \
    _Pragma("unroll")                                                         \
    for (int i_ = 0; i_ < PB; ++i_) {                                         \
        const int r_ = n0 + srow + i_*RPP;                                    \
        sb[i_] = (kv_ && r_ < N) ? *(const float4*)(B + (size_t)r_*ldb + kg_) \
                                 : zf4;                                       \
    }                                                                         \
} while (0)

#define LWRITE(BUF) do {                                                      \
    _Pragma("unroll")                                                         \
    for (int i_ = 0; i_ < PA; ++i_) {                                         \
        const int r_ = srow + i_*RPP;                                         \
        As[BUF][4*skq+0][r_] = sa[i_].x; As[BUF][4*skq+1][r_] = sa[i_].y;     \
        As[BUF][4*skq+2][r_] = sa[i_].z; As[BUF][4*skq+3][r_] = sa[i_].w;     \
    }                                                                         \
    _Pragma("unroll")                                                         \
    for (int i_ = 0; i_ < PB; ++i_) {                                         \
        const int r_ = srow + i_*RPP;                                         \
        Bs[BUF][4*skq+0][r_] = sb[i_].x; Bs[BUF][4*skq+1][r_] = sb[i_].y;     \
        Bs[BUF][4*skq+2][r_] = sb[i_].z; Bs[BUF][4*skq+3][r_] = sb[i_].w;     \
    }                                                                         \
} while (0)

    GLOAD(ks);
    LWRITE(0);
    __syncthreads();

    const int ar = ty * 8;
    const int br = w * 64 + tx * 8;

    for (int t = 0; t < nt; ++t) {
        const int cur = t & 1;
        if (t + 1 < nt) GLOAD(ks + (t + 1) * 32);
#pragma unroll
        for (int kk = 0; kk < 32; ++kk) {
            float4 a0 = *(const float4*)&As[cur][kk][ar];
            float4 a1 = *(const float4*)&As[cur][kk][ar + 4];
            float4 b0 = *(const float4*)&Bs[cur][kk][br];
            float4 b1 = *(const float4*)&Bs[cur][kk][br + 4];
            float av[8] = {a0.x,a0.y,a0.z,a0.w,a1.x,a1.y,a1.z,a1.w};
            float bv[8] = {b0.x,b0.y,b0.z,b0.w,b1.x,b1.y,b1.z,b1.w};
#pragma unroll
            for (int i = 0; i < 8; ++i)
#pragma unroll
                for (int j = 0; j < 8; ++j)
                    acc[i][j] = fmaf(av[i], bv[j], acc[i][j]);
        }
        __syncthreads();
        if (t + 1 < nt) {
            LWRITE((t + 1) & 1);
            __syncthreads();
        }
    }
#undef GLOAD
#undef LWRITE

    // ---- epilogue ----
    const int row0 = m0 + ty * 8;
    const int col  = n0 + br;
    const bool v0 = col < N;
    const bool v1 = col + 4 < N;

    if (MODE == 2) {
        float* Cz = C + (size_t)z * zstride;
#pragma unroll
        for (int i = 0; i < 8; ++i) {
            float* cr = Cz + (size_t)(row0 + i) * ldc + col;
            if (v0) *(float4*)(cr)     = make_float4(acc[i][0],acc[i][1],acc[i][2],acc[i][3]);
            if (v1) *(float4*)(cr + 4) = make_float4(acc[i][4],acc[i][5],acc[i][6],acc[i][7]);
        }
    } else {
        float s[8], t8[8];
        if (v0) {
            float4 ga = *(const float4*)(gamma + col);
            float4 va = *(const float4*)(var + col);
            float4 bi = *(const float4*)(bias + col);
            float4 mu = *(const float4*)(mean + col);
            float4 be = *(const float4*)(beta + col);
            s[0]=ga.x*rsqrtf(va.x+BN_EPS_F); s[1]=ga.y*rsqrtf(va.y+BN_EPS_F);
            s[2]=ga.z*rsqrtf(va.z+BN_EPS_F); s[3]=ga.w*rsqrtf(va.w+BN_EPS_F);
            t8[0]=fmaf(s[0],bi.x-mu.x,be.x); t8[1]=fmaf(s[1],bi.y-mu.y,be.y);
            t8[2]=fmaf(s[2],bi.z-mu.z,be.z); t8[3]=fmaf(s[3],bi.w-mu.w,be.w);
        }
        if (v1) {
            float4 ga = *(const float4*)(gamma + col + 4);
            float4 va = *(const float4*)(var + col + 4);
            float4 bi = *(const float4*)(bias + col + 4);
            float4 mu = *(const float4*)(mean + col + 4);
            float4 be = *(const float4*)(beta + col + 4);
            s[4]=ga.x*rsqrtf(va.x+BN_EPS_F); s[5]=ga.y*rsqrtf(va.y+BN_EPS_F);
            s[6]=ga.z*rsqrtf(va.z+BN_EPS_F); s[7]=ga.w*rsqrtf(va.w+BN_EPS_F);
            t8[4]=fmaf(s[4],bi.x-mu.x,be.x); t8[5]=fmaf(s[5],bi.y-mu.y,be.y);
            t8[6]=fmaf(s[6],bi.z-mu.z,be.z); t8[7]=fmaf(s[7],bi.w-mu.w,be.w);
        }
#pragma unroll
        for (int i = 0; i < 8; ++i) {
            float y[8];
#pragma unroll
            for (int j = 0; j < 8; ++j) {
                float yy = fmaf(s[j], acc[i][j], t8[j]);
                if (MODE == 0) yy = fmaxf(yy, 0.f);
                else           yy = 1.f / (1.f + expf(-yy));
                y[j] = yy;
            }
            float* cr = C + (size_t)(row0 + i) * ldc + col;
            if (v0) *(float4*)(cr)     = make_float4(y[0],y[1],y[2],y[3]);
            if (v1) *(float4*)(cr + 4) = make_float4(y[4],y[5],y[6],y[7]);
        }
    }
}

// ---------------------------------------------------------------------------
// Split-K=2 reduce for layer 2 + BN + relu -> h2 (2048 x 1000)
// ---------------------------------------------------------------------------
__global__ __launch_bounds__(256)
void reduce2_relu(const float* __restrict__ part,
                  const float* __restrict__ bias, const float* __restrict__ gamma,
                  const float* __restrict__ beta, const float* __restrict__ mean,
                  const float* __restrict__ var, float* __restrict__ h2)
{
    const int i = blockIdx.x * 256 + threadIdx.x;
    if (i >= 2048 * 250) return;
    const int m = i / 250;
    const int n = (i % 250) * 4;
    const size_t off = (size_t)m * 1000 + n;
    float4 a = *(const float4*)(part + off);
    float4 b = *(const float4*)(part + 2048000 + off);
    float4 ga = *(const float4*)(gamma + n);
    float4 va = *(const float4*)(var + n);
    float4 bi = *(const float4*)(bias + n);
    float4 mu = *(const float4*)(mean + n);
    float4 be = *(const float4*)(beta + n);
    float s0 = ga.x*rsqrtf(va.x+BN_EPS_F), s1 = ga.y*rsqrtf(va.y+BN_EPS_F);
    float s2 = ga.z*rsqrtf(va.z+BN_EPS_F), s3 = ga.w*rsqrtf(va.w+BN_EPS_F);
    float4 out;
    out.x = fmaxf(fmaf(s0, a.x + b.x + bi.x - mu.x, be.x), 0.f);
    out.y = fmaxf(fmaf(s1, a.y + b.y + bi.y - mu.y, be.y), 0.f);
    out.z = fmaxf(fmaf(s2, a.z + b.z + bi.z - mu.z, be.z), 0.f);
    out.w = fmaxf(fmaf(s3, a.w + b.w + bi.w - mu.w, be.w), 0.f);
    *(float4*)(h2 + off) = out;
}

// ---------------------------------------------------------------------------
// Split-K reduce for layer 3 + BN + sigmoid -> p (2048 x 300)
// ---------------------------------------------------------------------------
__global__ __launch_bounds__(256)
void reduce3_sigmoid(const float* __restrict__ part, int nz, size_t pstride,
                     const float* __restrict__ bias, const float* __restrict__ gamma,
                     const float* __restrict__ beta, const float* __restrict__ mean,
                     const float* __restrict__ var, float* __restrict__ p)
{
    const int i = blockIdx.x * 256 + threadIdx.x;
    if (i >= 2048 * 75) return;
    const int m = i / 75;
    const int n = (i % 75) * 4;
    const size_t off = (size_t)m * 304 + n;
    float d0 = 0.f, d1 = 0.f, d2 = 0.f, d3 = 0.f;
    for (int zz = 0; zz < nz; ++zz) {
        float4 v = *(const float4*)(part + zz * pstride + off);
        d0 += v.x; d1 += v.y; d2 += v.z; d3 += v.w;
    }
    float4 ga = *(const float4*)(gamma + n);
    float4 va = *(const float4*)(var + n);
    float4 bi = *(const float4*)(bias + n);
    float4 mu = *(const float4*)(mean + n);
    float4 be = *(const float4*)(beta + n);
    float s0 = ga.x*rsqrtf(va.x+BN_EPS_F), s1 = ga.y*rsqrtf(va.y+BN_EPS_F);
    float s2 = ga.z*rsqrtf(va.z+BN_EPS_F), s3 = ga.w*rsqrtf(va.w+BN_EPS_F);
    float4 out;
    out.x = 1.f/(1.f+expf(-(fmaf(s0, d0 + bi.x - mu.x, be.x))));
    out.y = 1.f/(1.f+expf(-(fmaf(s1, d1 + bi.y - mu.y, be.y))));
    out.z = 1.f/(1.f+expf(-(fmaf(s2, d2 + bi.z - mu.z, be.z))));
    out.w = 1.f/(1.f+expf(-(fmaf(s3, d3 + bi.w - mu.w, be.w))));
    *(float4*)(p + (size_t)m * 300 + n) = out;
}

// ---------------------------------------------------------------------------
// Lorentz spectrum: one block per batch row.
// ---------------------------------------------------------------------------
__global__ __launch_bounds__(320)
void lorentz_kernel(const float* __restrict__ P,     // 2048 x 300
                    const float* __restrict__ G,     // 2048 x 8
                    const float* __restrict__ wgrid, // 300
                    float* __restrict__ T)           // 2048 x 300
{
    __shared__ float s_w02[100], s_wp2[100], s_wp2g[100], s_g2[100];
    const int b   = blockIdx.x;
    const int tid = threadIdx.x;
    if (tid < 100) {
        const float* p = P + (size_t)b*300 + 3*tid;
        const float w0 = p[0]*5.f;
        const float wp = p[1]*5.f;
        const float g  = p[2]*0.5f;
        s_w02[tid]  = w0*w0;
        s_wp2[tid]  = wp*wp;
        s_g2[tid]   = g*g;
        s_wp2g[tid] = wp*wp*g;
    }
    __syncthreads();
    if (tid < 300) {
        const float wg = wgrid[tid];
        const float w2 = wg*wg;
        float e1 = 0.f, e2s = 0.f;
#pragma unroll 10
        for (int l = 0; l < 100; ++l) {
            const float s1    = s_w02[l] - w2;
            const float denom = fmaf(s1, s1, w2 * s_g2[l]);
            const float r     = __builtin_amdgcn_rcpf(denom);
            e1  = fmaf(s_wp2[l]*s1, r, e1);
            e2s = fmaf(s_wp2g[l],   r, e2s);
        }
        e1 += 10.f;
        const float e2  = e2s * wg;
        const float mag = sqrtf(fmaf(e1, e1, e2*e2));
        const float nn  = sqrtf(0.5f*(mag + e1));
        const float kk  = sqrtf(fmaxf(0.5f*(mag - e1), 0.f));
        const float d   = fmaxf(fmaxf(G[b*8+4], G[b*8+5]),
                                fmaxf(G[b*8+6], G[b*8+7]));
        const float ab  = expf(-0.006283185307179586f * d * kk);
        const float np1 = nn + 1.f;
        const float Tv  = 4.f*nn / fmaf(np1, np1, kk*kk) * ab;
        T[(size_t)b*300 + tid] = Tv;
    }
}

extern "C" void kernel_launch(void* const* d_in, const int* in_sizes, int n_in,
                              void* d_out, int out_size, void* d_ws, size_t ws_size,
                              hipStream_t stream) {
    const float* G      = (const float*)d_in[0];
    const float* W1     = (const float*)d_in[1];
    const float* b1     = (const float*)d_in[2];
    const float* gamma1 = (const float*)d_in[3];
    const float* beta1  = (const float*)d_in[4];
    const float* mean1  = (const float*)d_in[5];
    const float* var1   = (const float*)d_in[6];
    const float* W2     = (const float*)d_in[7];
    const float* b2     = (const float*)d_in[8];
    const float* gamma2 = (const float*)d_in[9];
    const float* beta2  = (const float*)d_in[10];
    const float* mean2  = (const float*)d_in[11];
    const float* var2   = (const float*)d_in[12];
    const float* W3     = (const float*)d_in[13];
    const float* b3     = (const float*)d_in[14];
    const float* gamma3 = (const float*)d_in[15];
    const float* beta3  = (const float*)d_in[16];
    const float* mean3  = (const float*)d_in[17];
    const float* var3   = (const float*)d_in[18];
    const float* wgrid  = (const float*)d_in[19];

    float* ws = (float*)d_ws;
    float* T  = (float*)d_out;
    float* h1 = ws;                               // 2,048,000 f

    const bool big = ws_size >= (size_t)32768000; // split-K2 layout needs 32.77 MB

    // Layer 1 (K=8, memory-bound)
    l1_kernel<<<2048, 256, 0, stream>>>(G, W1, b1, gamma1, beta1, mean1, var1, h1);

    if (big) {
        float* part2 = ws + 2048000;   // 2 x 2,048,000
        float* h2    = ws + 6144000;   // 2,048,000
        float* part3 = ws + 2048000;   // 6 x 622,592 = 3,735,552 (aliases part2)
        float* p     = ws;             // 614,400 (aliases dead h1)

        // Layer 2: split-K=2 -> partials (grid 8n x 32m x 2z = 512 blocks)
        gemm_f32<2, 2><<<dim3(8, 32, 2), 128, 0, stream>>>(
            h1, 1000, 1000, W2, 1000, 1000, 512,
            nullptr, nullptr, nullptr, nullptr, nullptr, part2, 1000, 2048000);
        reduce2_relu<<<2000, 256, 0, stream>>>(part2, b2, gamma2, beta2, mean2, var2, h2);

        // Layer 3: split-K=6 -> partials (grid 5n x 32m x 6z = 960 blocks)
        gemm_f32<1, 2><<<dim3(5, 32, 6), 64, 0, stream>>>(
            h2, 1000, 1000, W3, 300, 1000, 168,
            nullptr, nullptr, nullptr, nullptr, nullptr, part3, 304, 622592);
        reduce3_sigmoid<<<600, 256, 0, stream>>>(part3, 6, 622592,
            b3, gamma3, beta3, mean3, var3, p);

        lorentz_kernel<<<2048, 320, 0, stream>>>(p, G, wgrid, T);
    } else {
        float* h2    = ws + 2048000;   // 2,048,000
        float* part3 = ws;             // 3 x 622,592 = 1,867,776 (aliases dead h1)
        float* p     = ws + 4096000;   // 614,400
        // total footprint 18.84 MB (proven in rounds 1-2)

        // Layer 2: single pass, fused BN+relu (grid 8n x 32m = 256 blocks)
        gemm_f32<2, 0><<<dim3(8, 32, 1), 128, 0, stream>>>(
            h1, 1000, 1000, W2, 1000, 1000, 1000,
            b2, gamma2, beta2, mean2, var2, h2, 1000, 0);

        // Layer 3: split-K=3 -> partials (grid 5n x 32m x 3z = 480 blocks)
        gemm_f32<1, 2><<<dim3(5, 32, 3), 64, 0, stream>>>(
            h2, 1000, 1000, W3, 300, 1000, 336,
            nullptr, nullptr, nullptr, nullptr, nullptr, part3, 304, 622592);
        reduce3_sigmoid<<<600, 256, 0, stream>>>(part3, 3, 622592,
            b3, gamma3, beta3, mean3, var3, p);

        lorentz_kernel<<<2048, 320, 0, stream>>>(p, G, wgrid, T);
    }
}

// Round 4
// 438.357 us; speedup vs baseline: 1.7030x; 1.7030x over previous
//
#include <hip/hip_runtime.h>
#include <math.h>

#define BN_EPS_F 1e-5f

// ---------------------------------------------------------------------------
// Layer 1: K=8 — memory-bound, one thread per 4 outputs.
// ---------------------------------------------------------------------------
__global__ __launch_bounds__(256)
void l1_kernel(const float* __restrict__ G, const float* __restrict__ W1,
               const float* __restrict__ bias, const float* __restrict__ gamma,
               const float* __restrict__ beta, const float* __restrict__ mean,
               const float* __restrict__ var, float* __restrict__ h1)
{
    const int m = blockIdx.x;
    const int t = threadIdx.x;
    if (t >= 250) return;
    const int n = 4 * t;

    float4 g0 = *(const float4*)(G + (size_t)m * 8 + 0);
    float4 g1 = *(const float4*)(G + (size_t)m * 8 + 4);

    float4 bi = *(const float4*)(bias + n);
    float4 ga = *(const float4*)(gamma + n);
    float4 be = *(const float4*)(beta + n);
    float4 mu = *(const float4*)(mean + n);
    float4 va = *(const float4*)(var + n);

    float4 out;
    float* op = &out.x;
    const float* bip = &bi.x; const float* gap = &ga.x; const float* bep = &be.x;
    const float* mup = &mu.x; const float* vap = &va.x;
#pragma unroll
    for (int j = 0; j < 4; ++j) {
        const float* w = W1 + (size_t)(n + j) * 8;
        float4 w0 = *(const float4*)(w + 0);
        float4 w1 = *(const float4*)(w + 4);
        float d = g0.x*w0.x + g0.y*w0.y + g0.z*w0.z + g0.w*w0.w
                + g1.x*w1.x + g1.y*w1.y + g1.z*w1.z + g1.w*w1.w;
        float s  = gap[j] * rsqrtf(vap[j] + BN_EPS_F);
        float t0 = fmaf(s, bip[j] - mup[j], bep[j]);
        op[j] = fmaxf(fmaf(s, d, t0), 0.f);
    }
    *(float4*)(h1 + (size_t)m * 1000 + n) = out;
}

// ---------------------------------------------------------------------------
// fp32 NT GEMM. 64x64 tile, BK=32, 256 threads = 4 waves in 2x2 grid;
// wave = 8x8 lanes; per-thread 4x4 tile. Fragment reads are ds_read_b128
// with 8-way broadcast (conflict-free). Double-buffered LDS, register
// prefetch, straight-line staging. Register budget ~55 VGPR -> no spill.
// MODE 0: BN+relu, MODE 1: BN+sigmoid, MODE 2: raw partial (split-K, z).
// ---------------------------------------------------------------------------
template<int MODE>
__global__ __launch_bounds__(256, 2)
void gemm_t4(const float* __restrict__ A, int K, int lda,
             const float* __restrict__ B, int N, int ldb, int kchunk,
             const float* __restrict__ bias, const float* __restrict__ gamma,
             const float* __restrict__ beta, const float* __restrict__ mean,
             const float* __restrict__ var,
             float* __restrict__ C, int ldc, size_t zstride)
{
    __shared__ float As[2][32][68];
    __shared__ float Bs[2][32][68];

    const int tid  = threadIdx.x;
    const int w    = tid >> 6;
    const int lane = tid & 63;
    const int wx   = w & 1, wy = w >> 1;
    const int tx   = lane & 7, ty = lane >> 3;
    const int m0   = blockIdx.y * 64;
    const int n0   = blockIdx.x * 64;
    const int z    = blockIdx.z;
    const int ks   = z * kchunk;
    const int ke   = min(K, ks + kchunk);
    const int nt   = (ke - ks + 31) >> 5;

    const int srow = tid >> 3;     // 0..31
    const int skq  = tid & 7;      // 0..7 (16B chunk within BK)

    const float* Ar0 = A + (size_t)(m0 + srow)      * lda;
    const float* Ar1 = A + (size_t)(m0 + srow + 32) * lda;
    const float* Br0 = B + (size_t)(n0 + srow)      * ldb;
    const float* Br1 = B + (size_t)(n0 + srow + 32) * ldb;
    const bool bv0 = (n0 + srow)      < N;
    const bool bv1 = (n0 + srow + 32) < N;

    float4 pa0, pa1, pb0, pb1;
    const float4 zf4 = make_float4(0.f, 0.f, 0.f, 0.f);

    float acc[4][4];
#pragma unroll
    for (int i = 0; i < 4; ++i)
#pragma unroll
        for (int j = 0; j < 4; ++j) acc[i][j] = 0.f;

#define GLOAD(KT) do {                                                   \
    const int kg_ = (KT) + 4 * skq;                                      \
    const bool kv_ = kg_ < ke;                                           \
    pa0 = kv_         ? *(const float4*)(Ar0 + kg_) : zf4;               \
    pa1 = kv_         ? *(const float4*)(Ar1 + kg_) : zf4;               \
    pb0 = (kv_ && bv0)? *(const float4*)(Br0 + kg_) : zf4;               \
    pb1 = (kv_ && bv1)? *(const float4*)(Br1 + kg_) : zf4;               \
} while (0)

#define LWRITE(BUF) do {                                                 \
    As[BUF][4*skq+0][srow]    = pa0.x; As[BUF][4*skq+1][srow]    = pa0.y;\
    As[BUF][4*skq+2][srow]    = pa0.z; As[BUF][4*skq+3][srow]    = pa0.w;\
    As[BUF][4*skq+0][srow+32] = pa1.x; As[BUF][4*skq+1][srow+32] = pa1.y;\
    As[BUF][4*skq+2][srow+32] = pa1.z; As[BUF][4*skq+3][srow+32] = pa1.w;\
    Bs[BUF][4*skq+0][srow]    = pb0.x; Bs[BUF][4*skq+1][srow]    = pb0.y;\
    Bs[BUF][4*skq+2][srow]    = pb0.z; Bs[BUF][4*skq+3][srow]    = pb0.w;\
    Bs[BUF][4*skq+0][srow+32] = pb1.x; Bs[BUF][4*skq+1][srow+32] = pb1.y;\
    Bs[BUF][4*skq+2][srow+32] = pb1.z; Bs[BUF][4*skq+3][srow+32] = pb1.w;\
} while (0)

    GLOAD(ks);
    LWRITE(0);
    __syncthreads();

    const int ar = wy * 32 + ty * 4;
    const int br = wx * 32 + tx * 4;

    for (int t = 0; t < nt; ++t) {
        const int cur = t & 1;
        if (t + 1 < nt) GLOAD(ks + (t + 1) * 32);
#pragma unroll
        for (int kk = 0; kk < 32; ++kk) {
            float4 a = *(const float4*)&As[cur][kk][ar];
            float4 b = *(const float4*)&Bs[cur][kk][br];
            acc[0][0] = fmaf(a.x, b.x, acc[0][0]);
            acc[0][1] = fmaf(a.x, b.y, acc[0][1]);
            acc[0][2] = fmaf(a.x, b.z, acc[0][2]);
            acc[0][3] = fmaf(a.x, b.w, acc[0][3]);
            acc[1][0] = fmaf(a.y, b.x, acc[1][0]);
            acc[1][1] = fmaf(a.y, b.y, acc[1][1]);
            acc[1][2] = fmaf(a.y, b.z, acc[1][2]);
            acc[1][3] = fmaf(a.y, b.w, acc[1][3]);
            acc[2][0] = fmaf(a.z, b.x, acc[2][0]);
            acc[2][1] = fmaf(a.z, b.y, acc[2][1]);
            acc[2][2] = fmaf(a.z, b.z, acc[2][2]);
            acc[2][3] = fmaf(a.z, b.w, acc[2][3]);
            acc[3][0] = fmaf(a.w, b.x, acc[3][0]);
            acc[3][1] = fmaf(a.w, b.y, acc[3][1]);
            acc[3][2] = fmaf(a.w, b.z, acc[3][2]);
            acc[3][3] = fmaf(a.w, b.w, acc[3][3]);
        }
        __syncthreads();
        if (t + 1 < nt) {
            LWRITE((t + 1) & 1);
            __syncthreads();
        }
    }
#undef GLOAD
#undef LWRITE

    // ---- epilogue ----
    const int row = m0 + ar;
    const int col = n0 + br;
    if (col < N) {                 // col%4==0, N%4==0 -> whole float4 valid
        if (MODE == 2) {
            float* Cz = C + (size_t)z * zstride;
#pragma unroll
            for (int i = 0; i < 4; ++i)
                *(float4*)(Cz + (size_t)(row + i) * ldc + col) =
                    make_float4(acc[i][0], acc[i][1], acc[i][2], acc[i][3]);
        } else {
            float4 ga = *(const float4*)(gamma + col);
            float4 va = *(const float4*)(var + col);
            float4 bi = *(const float4*)(bias + col);
            float4 mu = *(const float4*)(mean + col);
            float4 be = *(const float4*)(beta + col);
            float s0 = ga.x * rsqrtf(va.x + BN_EPS_F);
            float s1 = ga.y * rsqrtf(va.y + BN_EPS_F);
            float s2 = ga.z * rsqrtf(va.z + BN_EPS_F);
            float s3 = ga.w * rsqrtf(va.w + BN_EPS_F);
            float t0 = fmaf(s0, bi.x - mu.x, be.x);
            float t1 = fmaf(s1, bi.y - mu.y, be.y);
            float t2 = fmaf(s2, bi.z - mu.z, be.z);
            float t3 = fmaf(s3, bi.w - mu.w, be.w);
#pragma unroll
            for (int i = 0; i < 4; ++i) {
                float y0 = fmaf(s0, acc[i][0], t0);
                float y1 = fmaf(s1, acc[i][1], t1);
                float y2 = fmaf(s2, acc[i][2], t2);
                float y3 = fmaf(s3, acc[i][3], t3);
                if (MODE == 0) {
                    y0 = fmaxf(y0, 0.f); y1 = fmaxf(y1, 0.f);
                    y2 = fmaxf(y2, 0.f); y3 = fmaxf(y3, 0.f);
                } else {
                    y0 = 1.f/(1.f+expf(-y0)); y1 = 1.f/(1.f+expf(-y1));
                    y2 = 1.f/(1.f+expf(-y2)); y3 = 1.f/(1.f+expf(-y3));
                }
                *(float4*)(C + (size_t)(row + i) * ldc + col) =
                    make_float4(y0, y1, y2, y3);
            }
        }
    }
}

// ---------------------------------------------------------------------------
// Split-K reduce for layer 3 + BN + sigmoid -> p (2048 x 300)
// ---------------------------------------------------------------------------
__global__ __launch_bounds__(256)
void reduce3_sigmoid(const float* __restrict__ part, int nz, size_t pstride,
                     const float* __restrict__ bias, const float* __restrict__ gamma,
                     const float* __restrict__ beta, const float* __restrict__ mean,
                     const float* __restrict__ var, float* __restrict__ p)
{
    const int i = blockIdx.x * 256 + threadIdx.x;
    if (i >= 2048 * 75) return;
    const int m = i / 75;
    const int n = (i % 75) * 4;
    const size_t off = (size_t)m * 304 + n;
    float d0 = 0.f, d1 = 0.f, d2 = 0.f, d3 = 0.f;
    for (int zz = 0; zz < nz; ++zz) {
        float4 v = *(const float4*)(part + zz * pstride + off);
        d0 += v.x; d1 += v.y; d2 += v.z; d3 += v.w;
    }
    float4 ga = *(const float4*)(gamma + n);
    float4 va = *(const float4*)(var + n);
    float4 bi = *(const float4*)(bias + n);
    float4 mu = *(const float4*)(mean + n);
    float4 be = *(const float4*)(beta + n);
    float s0 = ga.x*rsqrtf(va.x+BN_EPS_F), s1 = ga.y*rsqrtf(va.y+BN_EPS_F);
    float s2 = ga.z*rsqrtf(va.z+BN_EPS_F), s3 = ga.w*rsqrtf(va.w+BN_EPS_F);
    float4 out;
    out.x = 1.f/(1.f+expf(-(fmaf(s0, d0 + bi.x - mu.x, be.x))));
    out.y = 1.f/(1.f+expf(-(fmaf(s1, d1 + bi.y - mu.y, be.y))));
    out.z = 1.f/(1.f+expf(-(fmaf(s2, d2 + bi.z - mu.z, be.z))));
    out.w = 1.f/(1.f+expf(-(fmaf(s3, d3 + bi.w - mu.w, be.w))));
    *(float4*)(p + (size_t)m * 300 + n) = out;
}

// ---------------------------------------------------------------------------
// Lorentz spectrum: one block per batch row.
// ---------------------------------------------------------------------------
__global__ __launch_bounds__(320)
void lorentz_kernel(const float* __restrict__ P,     // 2048 x 300
                    const float* __restrict__ G,     // 2048 x 8
                    const float* __restrict__ wgrid, // 300
                    float* __restrict__ T)           // 2048 x 300
{
    __shared__ float s_w02[100], s_wp2[100], s_wp2g[100], s_g2[100];
    const int b   = blockIdx.x;
    const int tid = threadIdx.x;
    if (tid < 100) {
        const float* p = P + (size_t)b*300 + 3*tid;
        const float w0 = p[0]*5.f;
        const float wp = p[1]*5.f;
        const float g  = p[2]*0.5f;
        s_w02[tid]  = w0*w0;
        s_wp2[tid]  = wp*wp;
        s_g2[tid]   = g*g;
        s_wp2g[tid] = wp*wp*g;
    }
    __syncthreads();
    if (tid < 300) {
        const float wg = wgrid[tid];
        const float w2 = wg*wg;
        float e1 = 0.f, e2s = 0.f;
#pragma unroll 10
        for (int l = 0; l < 100; ++l) {
            const float s1    = s_w02[l] - w2;
            const float denom = fmaf(s1, s1, w2 * s_g2[l]);
            const float r     = __builtin_amdgcn_rcpf(denom);
            e1  = fmaf(s_wp2[l]*s1, r, e1);
            e2s = fmaf(s_wp2g[l],   r, e2s);
        }
        e1 += 10.f;
        const float e2  = e2s * wg;
        const float mag = sqrtf(fmaf(e1, e1, e2*e2));
        const float nn  = sqrtf(0.5f*(mag + e1));
        const float kk  = sqrtf(fmaxf(0.5f*(mag - e1), 0.f));
        const float d   = fmaxf(fmaxf(G[b*8+4], G[b*8+5]),
                                fmaxf(G[b*8+6], G[b*8+7]));
        const float ab  = expf(-0.006283185307179586f * d * kk);
        const float np1 = nn + 1.f;
        const float Tv  = 4.f*nn / fmaf(np1, np1, kk*kk) * ab;
        T[(size_t)b*300 + tid] = Tv;
    }
}

extern "C" void kernel_launch(void* const* d_in, const int* in_sizes, int n_in,
                              void* d_out, int out_size, void* d_ws, size_t ws_size,
                              hipStream_t stream) {
    const float* G      = (const float*)d_in[0];
    const float* W1     = (const float*)d_in[1];
    const float* b1     = (const float*)d_in[2];
    const float* gamma1 = (const float*)d_in[3];
    const float* beta1  = (const float*)d_in[4];
    const float* mean1  = (const float*)d_in[5];
    const float* var1   = (const float*)d_in[6];
    const float* W2     = (const float*)d_in[7];
    const float* b2     = (const float*)d_in[8];
    const float* gamma2 = (const float*)d_in[9];
    const float* beta2  = (const float*)d_in[10];
    const float* mean2  = (const float*)d_in[11];
    const float* var2   = (const float*)d_in[12];
    const float* W3     = (const float*)d_in[13];
    const float* b3     = (const float*)d_in[14];
    const float* gamma3 = (const float*)d_in[15];
    const float* beta3  = (const float*)d_in[16];
    const float* mean3  = (const float*)d_in[17];
    const float* var3   = (const float*)d_in[18];
    const float* wgrid  = (const float*)d_in[19];

    float* ws = (float*)d_ws;
    float* T  = (float*)d_out;

    // Fixed 18.84 MB layout (proven in rounds 1-2), no ws_size branching.
    float* h1    = ws;                 // 2,048,000 f
    float* h2    = ws + 2048000;       // 2,048,000 f
    float* part3 = ws;                 // aliases h1 (dead after L2): 3 x 622,592
    float* p     = ws + 4096000;       // 614,400 f

    // Layer 1 (K=8, memory-bound)
    l1_kernel<<<2048, 256, 0, stream>>>(G, W1, b1, gamma1, beta1, mean1, var1, h1);

    // Layer 2: 2048x1000, K=1000, fused BN+relu (grid 16n x 32m = 512 blocks)
    gemm_t4<0><<<dim3(16, 32, 1), 256, 0, stream>>>(
        h1, 1000, 1000, W2, 1000, 1000, 1000,
        b2, gamma2, beta2, mean2, var2, h2, 1000, 0);

    // Layer 3: 2048x300, K=1000, split-K=3 (grid 5n x 32m x 3z = 480 blocks)
    gemm_t4<2><<<dim3(5, 32, 3), 256, 0, stream>>>(
        h2, 1000, 1000, W3, 300, 1000, 336,
        nullptr, nullptr, nullptr, nullptr, nullptr, part3, 304, 622592);

    // Reduce partials + BN + sigmoid -> p
    reduce3_sigmoid<<<600, 256, 0, stream>>>(part3, 3, 622592,
        b3, gamma3, beta3, mean3, var3, p);

    // Lorentz spectrum -> T
    lorentz_kernel<<<2048, 320, 0, stream>>>(p, G, wgrid, T);
}

// Round 5
// 173.041 us; speedup vs baseline: 4.3140x; 2.5333x over previous
//
#include <hip/hip_runtime.h>
#include <math.h>

#define BN_EPS_F 1e-5f

// ---------------------------------------------------------------------------
// Layer 1: K=8 — memory-bound, one thread per 4 outputs.
// ---------------------------------------------------------------------------
__global__ __launch_bounds__(256)
void l1_kernel(const float* __restrict__ G, const float* __restrict__ W1,
               const float* __restrict__ bias, const float* __restrict__ gamma,
               const float* __restrict__ beta, const float* __restrict__ mean,
               const float* __restrict__ var, float* __restrict__ h1)
{
    const int m = blockIdx.x;
    const int t = threadIdx.x;
    if (t >= 250) return;
    const int n = 4 * t;

    float4 g0 = *(const float4*)(G + (size_t)m * 8 + 0);
    float4 g1 = *(const float4*)(G + (size_t)m * 8 + 4);

    float4 bi = *(const float4*)(bias + n);
    float4 ga = *(const float4*)(gamma + n);
    float4 be = *(const float4*)(beta + n);
    float4 mu = *(const float4*)(mean + n);
    float4 va = *(const float4*)(var + n);

    float4 out;
    float* op = &out.x;
    const float* bip = &bi.x; const float* gap = &ga.x; const float* bep = &be.x;
    const float* mup = &mu.x; const float* vap = &va.x;
#pragma unroll
    for (int j = 0; j < 4; ++j) {
        const float* w = W1 + (size_t)(n + j) * 8;
        float4 w0 = *(const float4*)(w + 0);
        float4 w1 = *(const float4*)(w + 4);
        float d = g0.x*w0.x + g0.y*w0.y + g0.z*w0.z + g0.w*w0.w
                + g1.x*w1.x + g1.y*w1.y + g1.z*w1.z + g1.w*w1.w;
        float s  = gap[j] * rsqrtf(vap[j] + BN_EPS_F);
        float t0 = fmaf(s, bip[j] - mup[j], bep[j]);
        op[j] = fmaxf(fmaf(s, d, t0), 0.f);
    }
    *(float4*)(h1 + (size_t)m * 1000 + n) = out;
}

// ---------------------------------------------------------------------------
// fp32 NT GEMM — round-1 pipeline (single LDS buffer, straight-line staging,
// NO register liveness across barriers -> no spills), round-4 geometry
// (256 threads = 4 waves 2x2, 64x64 tile, 4x4/thread, BK=32).
// Fragment reads: ds_read_b128, 8-way same-address broadcast (conflict-free).
// MODE 0: BN+relu, MODE 1: BN+sigmoid, MODE 2: raw partial (split-K via z).
// ---------------------------------------------------------------------------
template<int MODE>
__global__ __launch_bounds__(256)
void gemm_s1(const float* __restrict__ A, int K, int lda,
             const float* __restrict__ B, int N, int ldb, int kchunk,
             const float* __restrict__ bias, const float* __restrict__ gamma,
             const float* __restrict__ beta, const float* __restrict__ mean,
             const float* __restrict__ var,
             float* __restrict__ C, int ldc, size_t zstride)
{
    __shared__ float As[32][68];
    __shared__ float Bs[32][68];

    const int tid  = threadIdx.x;
    const int w    = tid >> 6;
    const int lane = tid & 63;
    const int wx   = w & 1, wy = w >> 1;
    const int tx   = lane & 7, ty = lane >> 3;
    const int m0   = blockIdx.y * 64;
    const int n0   = blockIdx.x * 64;
    const int z    = blockIdx.z;
    const int ks   = z * kchunk;
    const int ke   = min(K, ks + kchunk);
    const int nt   = (ke - ks + 31) >> 5;

    const int srow = tid >> 3;     // 0..31
    const int skq  = tid & 7;      // 16B chunk within BK=32

    const float* Ar0 = A + (size_t)(m0 + srow)      * lda;
    const float* Ar1 = A + (size_t)(m0 + srow + 32) * lda;
    const float* Br0 = B + (size_t)(n0 + srow)      * ldb;
    const float* Br1 = B + (size_t)(n0 + srow + 32) * ldb;
    const bool bv0 = (n0 + srow)      < N;
    const bool bv1 = (n0 + srow + 32) < N;

    float acc[4][4];
#pragma unroll
    for (int i = 0; i < 4; ++i)
#pragma unroll
        for (int j = 0; j < 4; ++j) acc[i][j] = 0.f;

    const int ar = wy * 32 + ty * 4;
    const int br = wx * 32 + tx * 4;
    const float4 zf4 = make_float4(0.f, 0.f, 0.f, 0.f);

    for (int t = 0; t < nt; ++t) {
        // ---- stage tile t: load -> immediately write LDS (no cross-barrier regs)
        {
            const int kg  = ks + t * 32 + 4 * skq;
            const bool kv = kg < ke;                 // K%4==0 -> all-or-nothing
            float4 pa0 = kv          ? *(const float4*)(Ar0 + kg) : zf4;
            float4 pa1 = kv          ? *(const float4*)(Ar1 + kg) : zf4;
            float4 pb0 = (kv && bv0) ? *(const float4*)(Br0 + kg) : zf4;
            float4 pb1 = (kv && bv1) ? *(const float4*)(Br1 + kg) : zf4;
            As[4*skq+0][srow]    = pa0.x; As[4*skq+1][srow]    = pa0.y;
            As[4*skq+2][srow]    = pa0.z; As[4*skq+3][srow]    = pa0.w;
            As[4*skq+0][srow+32] = pa1.x; As[4*skq+1][srow+32] = pa1.y;
            As[4*skq+2][srow+32] = pa1.z; As[4*skq+3][srow+32] = pa1.w;
            Bs[4*skq+0][srow]    = pb0.x; Bs[4*skq+1][srow]    = pb0.y;
            Bs[4*skq+2][srow]    = pb0.z; Bs[4*skq+3][srow]    = pb0.w;
            Bs[4*skq+0][srow+32] = pb1.x; Bs[4*skq+1][srow+32] = pb1.y;
            Bs[4*skq+2][srow+32] = pb1.z; Bs[4*skq+3][srow+32] = pb1.w;
        }
        __syncthreads();
        // ---- MAC (partial unroll bounds scheduler hoisting -> low VGPR)
#pragma unroll 8
        for (int kk = 0; kk < 32; ++kk) {
            float4 a = *(const float4*)&As[kk][ar];
            float4 b = *(const float4*)&Bs[kk][br];
            acc[0][0] = fmaf(a.x, b.x, acc[0][0]);
            acc[0][1] = fmaf(a.x, b.y, acc[0][1]);
            acc[0][2] = fmaf(a.x, b.z, acc[0][2]);
            acc[0][3] = fmaf(a.x, b.w, acc[0][3]);
            acc[1][0] = fmaf(a.y, b.x, acc[1][0]);
            acc[1][1] = fmaf(a.y, b.y, acc[1][1]);
            acc[1][2] = fmaf(a.y, b.z, acc[1][2]);
            acc[1][3] = fmaf(a.y, b.w, acc[1][3]);
            acc[2][0] = fmaf(a.z, b.x, acc[2][0]);
            acc[2][1] = fmaf(a.z, b.y, acc[2][1]);
            acc[2][2] = fmaf(a.z, b.z, acc[2][2]);
            acc[2][3] = fmaf(a.z, b.w, acc[2][3]);
            acc[3][0] = fmaf(a.w, b.x, acc[3][0]);
            acc[3][1] = fmaf(a.w, b.y, acc[3][1]);
            acc[3][2] = fmaf(a.w, b.z, acc[3][2]);
            acc[3][3] = fmaf(a.w, b.w, acc[3][3]);
        }
        __syncthreads();
    }

    // ---- epilogue ----
    const int row = m0 + ar;
    const int col = n0 + br;
    if (col < N) {                 // col%4==0, N%4==0 -> whole float4 valid
        if (MODE == 2) {
            float* Cz = C + (size_t)z * zstride;
#pragma unroll
            for (int i = 0; i < 4; ++i)
                *(float4*)(Cz + (size_t)(row + i) * ldc + col) =
                    make_float4(acc[i][0], acc[i][1], acc[i][2], acc[i][3]);
        } else {
            float4 ga = *(const float4*)(gamma + col);
            float4 va = *(const float4*)(var + col);
            float4 bi = *(const float4*)(bias + col);
            float4 mu = *(const float4*)(mean + col);
            float4 be = *(const float4*)(beta + col);
            float s0 = ga.x * rsqrtf(va.x + BN_EPS_F);
            float s1 = ga.y * rsqrtf(va.y + BN_EPS_F);
            float s2 = ga.z * rsqrtf(va.z + BN_EPS_F);
            float s3 = ga.w * rsqrtf(va.w + BN_EPS_F);
            float t0 = fmaf(s0, bi.x - mu.x, be.x);
            float t1 = fmaf(s1, bi.y - mu.y, be.y);
            float t2 = fmaf(s2, bi.z - mu.z, be.z);
            float t3 = fmaf(s3, bi.w - mu.w, be.w);
#pragma unroll
            for (int i = 0; i < 4; ++i) {
                float y0 = fmaf(s0, acc[i][0], t0);
                float y1 = fmaf(s1, acc[i][1], t1);
                float y2 = fmaf(s2, acc[i][2], t2);
                float y3 = fmaf(s3, acc[i][3], t3);
                if (MODE == 0) {
                    y0 = fmaxf(y0, 0.f); y1 = fmaxf(y1, 0.f);
                    y2 = fmaxf(y2, 0.f); y3 = fmaxf(y3, 0.f);
                } else {
                    y0 = 1.f/(1.f+expf(-y0)); y1 = 1.f/(1.f+expf(-y1));
                    y2 = 1.f/(1.f+expf(-y2)); y3 = 1.f/(1.f+expf(-y3));
                }
                *(float4*)(C + (size_t)(row + i) * ldc + col) =
                    make_float4(y0, y1, y2, y3);
            }
        }
    }
}

// ---------------------------------------------------------------------------
// Split-K reduce for layer 3 + BN + sigmoid -> p (2048 x 300)
// ---------------------------------------------------------------------------
__global__ __launch_bounds__(256)
void reduce3_sigmoid(const float* __restrict__ part, int nz, size_t pstride,
                     const float* __restrict__ bias, const float* __restrict__ gamma,
                     const float* __restrict__ beta, const float* __restrict__ mean,
                     const float* __restrict__ var, float* __restrict__ p)
{
    const int i = blockIdx.x * 256 + threadIdx.x;
    if (i >= 2048 * 75) return;
    const int m = i / 75;
    const int n = (i % 75) * 4;
    const size_t off = (size_t)m * 304 + n;
    float d0 = 0.f, d1 = 0.f, d2 = 0.f, d3 = 0.f;
    for (int zz = 0; zz < nz; ++zz) {
        float4 v = *(const float4*)(part + zz * pstride + off);
        d0 += v.x; d1 += v.y; d2 += v.z; d3 += v.w;
    }
    float4 ga = *(const float4*)(gamma + n);
    float4 va = *(const float4*)(var + n);
    float4 bi = *(const float4*)(bias + n);
    float4 mu = *(const float4*)(mean + n);
    float4 be = *(const float4*)(beta + n);
    float s0 = ga.x*rsqrtf(va.x+BN_EPS_F), s1 = ga.y*rsqrtf(va.y+BN_EPS_F);
    float s2 = ga.z*rsqrtf(va.z+BN_EPS_F), s3 = ga.w*rsqrtf(va.w+BN_EPS_F);
    float4 out;
    out.x = 1.f/(1.f+expf(-(fmaf(s0, d0 + bi.x - mu.x, be.x))));
    out.y = 1.f/(1.f+expf(-(fmaf(s1, d1 + bi.y - mu.y, be.y))));
    out.z = 1.f/(1.f+expf(-(fmaf(s2, d2 + bi.z - mu.z, be.z))));
    out.w = 1.f/(1.f+expf(-(fmaf(s3, d3 + bi.w - mu.w, be.w))));
    *(float4*)(p + (size_t)m * 300 + n) = out;
}

// ---------------------------------------------------------------------------
// Lorentz spectrum: one block per batch row.
// ---------------------------------------------------------------------------
__global__ __launch_bounds__(320)
void lorentz_kernel(const float* __restrict__ P,     // 2048 x 300
                    const float* __restrict__ G,     // 2048 x 8
                    const float* __restrict__ wgrid, // 300
                    float* __restrict__ T)           // 2048 x 300
{
    __shared__ float s_w02[100], s_wp2[100], s_wp2g[100], s_g2[100];
    const int b   = blockIdx.x;
    const int tid = threadIdx.x;
    if (tid < 100) {
        const float* p = P + (size_t)b*300 + 3*tid;
        const float w0 = p[0]*5.f;
        const float wp = p[1]*5.f;
        const float g  = p[2]*0.5f;
        s_w02[tid]  = w0*w0;
        s_wp2[tid]  = wp*wp;
        s_g2[tid]   = g*g;
        s_wp2g[tid] = wp*wp*g;
    }
    __syncthreads();
    if (tid < 300) {
        const float wg = wgrid[tid];
        const float w2 = wg*wg;
        float e1 = 0.f, e2s = 0.f;
#pragma unroll 10
        for (int l = 0; l < 100; ++l) {
            const float s1    = s_w02[l] - w2;
            const float denom = fmaf(s1, s1, w2 * s_g2[l]);
            const float r     = __builtin_amdgcn_rcpf(denom);
            e1  = fmaf(s_wp2[l]*s1, r, e1);
            e2s = fmaf(s_wp2g[l],   r, e2s);
        }
        e1 += 10.f;
        const float e2  = e2s * wg;
        const float mag = sqrtf(fmaf(e1, e1, e2*e2));
        const float nn  = sqrtf(0.5f*(mag + e1));
        const float kk  = sqrtf(fmaxf(0.5f*(mag - e1), 0.f));
        const float d   = fmaxf(fmaxf(G[b*8+4], G[b*8+5]),
                                fmaxf(G[b*8+6], G[b*8+7]));
        const float ab  = expf(-0.006283185307179586f * d * kk);
        const float np1 = nn + 1.f;
        const float Tv  = 4.f*nn / fmaf(np1, np1, kk*kk) * ab;
        T[(size_t)b*300 + tid] = Tv;
    }
}

extern "C" void kernel_launch(void* const* d_in, const int* in_sizes, int n_in,
                              void* d_out, int out_size, void* d_ws, size_t ws_size,
                              hipStream_t stream) {
    const float* G      = (const float*)d_in[0];
    const float* W1     = (const float*)d_in[1];
    const float* b1     = (const float*)d_in[2];
    const float* gamma1 = (const float*)d_in[3];
    const float* beta1  = (const float*)d_in[4];
    const float* mean1  = (const float*)d_in[5];
    const float* var1   = (const float*)d_in[6];
    const float* W2     = (const float*)d_in[7];
    const float* b2     = (const float*)d_in[8];
    const float* gamma2 = (const float*)d_in[9];
    const float* beta2  = (const float*)d_in[10];
    const float* mean2  = (const float*)d_in[11];
    const float* var2   = (const float*)d_in[12];
    const float* W3     = (const float*)d_in[13];
    const float* b3     = (const float*)d_in[14];
    const float* gamma3 = (const float*)d_in[15];
    const float* beta3  = (const float*)d_in[16];
    const float* mean3  = (const float*)d_in[17];
    const float* var3   = (const float*)d_in[18];
    const float* wgrid  = (const float*)d_in[19];

    float* ws = (float*)d_ws;
    float* T  = (float*)d_out;

    // Fixed 18.84 MB layout (proven), no ws_size branching.
    float* h1    = ws;                 // 2,048,000 f
    float* h2    = ws + 2048000;       // 2,048,000 f
    float* part3 = ws;                 // aliases h1 (dead after L2): 3 x 622,592
    float* p     = ws + 4096000;       // 614,400 f

    // Layer 1 (K=8, memory-bound)
    l1_kernel<<<2048, 256, 0, stream>>>(G, W1, b1, gamma1, beta1, mean1, var1, h1);

    // Layer 2: 2048x1000, K=1000, fused BN+relu (grid 16n x 32m = 512 blocks)
    gemm_s1<0><<<dim3(16, 32, 1), 256, 0, stream>>>(
        h1, 1000, 1000, W2, 1000, 1000, 1000,
        b2, gamma2, beta2, mean2, var2, h2, 1000, 0);

    // Layer 3: 2048x300, K=1000, split-K=3 (grid 5n x 32m x 3z = 480 blocks)
    gemm_s1<2><<<dim3(5, 32, 3), 256, 0, stream>>>(
        h2, 1000, 1000, W3, 300, 1000, 336,
        nullptr, nullptr, nullptr, nullptr, nullptr, part3, 304, 622592);

    // Reduce partials + BN + sigmoid -> p
    reduce3_sigmoid<<<600, 256, 0, stream>>>(part3, 3, 622592,
        b3, gamma3, beta3, mean3, var3, p);

    // Lorentz spectrum -> T
    lorentz_kernel<<<2048, 320, 0, stream>>>(p, G, wgrid, T);
}

// Round 6
// 170.829 us; speedup vs baseline: 4.3699x; 1.0130x over previous
//
#include <hip/hip_runtime.h>
#include <math.h>

#define BN_EPS_F 1e-5f

// ---------------------------------------------------------------------------
// Layer 1: K=8 — memory-bound, one thread per 4 outputs.
// ---------------------------------------------------------------------------
__global__ __launch_bounds__(256)
void l1_kernel(const float* __restrict__ G, const float* __restrict__ W1,
               const float* __restrict__ bias, const float* __restrict__ gamma,
               const float* __restrict__ beta, const float* __restrict__ mean,
               const float* __restrict__ var, float* __restrict__ h1)
{
    const int m = blockIdx.x;
    const int t = threadIdx.x;
    if (t >= 250) return;
    const int n = 4 * t;

    float4 g0 = *(const float4*)(G + (size_t)m * 8 + 0);
    float4 g1 = *(const float4*)(G + (size_t)m * 8 + 4);

    float4 bi = *(const float4*)(bias + n);
    float4 ga = *(const float4*)(gamma + n);
    float4 be = *(const float4*)(beta + n);
    float4 mu = *(const float4*)(mean + n);
    float4 va = *(const float4*)(var + n);

    float4 out;
    float* op = &out.x;
    const float* bip = &bi.x; const float* gap = &ga.x; const float* bep = &be.x;
    const float* mup = &mu.x; const float* vap = &va.x;
#pragma unroll
    for (int j = 0; j < 4; ++j) {
        const float* w = W1 + (size_t)(n + j) * 8;
        float4 w0 = *(const float4*)(w + 0);
        float4 w1 = *(const float4*)(w + 4);
        float d = g0.x*w0.x + g0.y*w0.y + g0.z*w0.z + g0.w*w0.w
                + g1.x*w1.x + g1.y*w1.y + g1.z*w1.z + g1.w*w1.w;
        float s  = gap[j] * rsqrtf(vap[j] + BN_EPS_F);
        float t0 = fmaf(s, bip[j] - mup[j], bep[j]);
        op[j] = fmaxf(fmaf(s, d, t0), 0.f);
    }
    *(float4*)(h1 + (size_t)m * 1000 + n) = out;
}

// ---------------------------------------------------------------------------
// fp32 NT GEMM — 64(M) x 128(N) tile, BK=32, 256 threads = 4 waves (2x2):
// wave covers 32M x 64N, lane (8x8 grid) computes 4M x 8N. Per kk: 3 x
// ds_read_b128 per 32 FMA (1.5 B/FMA — halves LDS pipe load vs 4x4).
// Single LDS buffer, straight-line staging, NO register liveness across
// barriers (round-5 proven spill-free recipe), #pragma unroll 4 on MAC.
// MODE 0: BN+relu, MODE 1: BN+sigmoid, MODE 2: raw partial (split-K via z).
// Requires: ldc >= round_up(max written col + 1, 8); K % 4 == 0.
// ---------------------------------------------------------------------------
template<int MODE>
__global__ __launch_bounds__(256)
void gemm_w(const float* __restrict__ A, int K, int lda,
            const float* __restrict__ B, int N, int ldb, int kchunk,
            const float* __restrict__ bias, const float* __restrict__ gamma,
            const float* __restrict__ beta, const float* __restrict__ mean,
            const float* __restrict__ var,
            float* __restrict__ C, int ldc, size_t zstride)
{
    __shared__ float As[32][68];
    __shared__ float Bs[32][132];

    const int tid  = threadIdx.x;
    const int w    = tid >> 6;
    const int lane = tid & 63;
    const int wx   = w & 1, wy = w >> 1;       // wx: N half, wy: M half
    const int tx   = lane & 7, ty = lane >> 3;
    const int m0   = blockIdx.y * 64;
    const int n0   = blockIdx.x * 128;
    const int z    = blockIdx.z;
    const int ks   = z * kchunk;
    const int ke   = min(K, ks + kchunk);
    const int nt   = (ke - ks + 31) >> 5;

    const int srow = tid >> 3;     // 0..31
    const int skq  = tid & 7;      // 16B chunk within BK=32

    const float* Ar0 = A + (size_t)(m0 + srow)      * lda;
    const float* Ar1 = A + (size_t)(m0 + srow + 32) * lda;
    const float* Br0 = B + (size_t)(n0 + srow)      * ldb;
    const float* Br1 = B + (size_t)(n0 + srow + 32) * ldb;
    const float* Br2 = B + (size_t)(n0 + srow + 64) * ldb;
    const float* Br3 = B + (size_t)(n0 + srow + 96) * ldb;
    const bool bb0 = (n0 + srow)      < N;
    const bool bb1 = (n0 + srow + 32) < N;
    const bool bb2 = (n0 + srow + 64) < N;
    const bool bb3 = (n0 + srow + 96) < N;

    float acc[4][8];
#pragma unroll
    for (int i = 0; i < 4; ++i)
#pragma unroll
        for (int j = 0; j < 8; ++j) acc[i][j] = 0.f;

    const int ar = wy * 32 + ty * 4;
    const int br = wx * 64 + tx * 8;
    const float4 zf4 = make_float4(0.f, 0.f, 0.f, 0.f);

    for (int t = 0; t < nt; ++t) {
        // ---- stage tile t (load -> immediate LDS write; nothing crosses barrier)
        {
            const int kg  = ks + t * 32 + 4 * skq;
            const bool kv = kg < ke;                 // ke%4==0 -> all-or-nothing
            float4 a0 = kv          ? *(const float4*)(Ar0 + kg) : zf4;
            float4 a1 = kv          ? *(const float4*)(Ar1 + kg) : zf4;
            float4 q0 = (kv && bb0) ? *(const float4*)(Br0 + kg) : zf4;
            float4 q1 = (kv && bb1) ? *(const float4*)(Br1 + kg) : zf4;
            float4 q2 = (kv && bb2) ? *(const float4*)(Br2 + kg) : zf4;
            float4 q3 = (kv && bb3) ? *(const float4*)(Br3 + kg) : zf4;
            As[4*skq+0][srow]    = a0.x; As[4*skq+1][srow]    = a0.y;
            As[4*skq+2][srow]    = a0.z; As[4*skq+3][srow]    = a0.w;
            As[4*skq+0][srow+32] = a1.x; As[4*skq+1][srow+32] = a1.y;
            As[4*skq+2][srow+32] = a1.z; As[4*skq+3][srow+32] = a1.w;
            Bs[4*skq+0][srow]    = q0.x; Bs[4*skq+1][srow]    = q0.y;
            Bs[4*skq+2][srow]    = q0.z; Bs[4*skq+3][srow]    = q0.w;
            Bs[4*skq+0][srow+32] = q1.x; Bs[4*skq+1][srow+32] = q1.y;
            Bs[4*skq+2][srow+32] = q1.z; Bs[4*skq+3][srow+32] = q1.w;
            Bs[4*skq+0][srow+64] = q2.x; Bs[4*skq+1][srow+64] = q2.y;
            Bs[4*skq+2][srow+64] = q2.z; Bs[4*skq+3][srow+64] = q2.w;
            Bs[4*skq+0][srow+96] = q3.x; Bs[4*skq+1][srow+96] = q3.y;
            Bs[4*skq+2][srow+96] = q3.z; Bs[4*skq+3][srow+96] = q3.w;
        }
        __syncthreads();
        // ---- MAC: 3 x ds_read_b128 per 32 FMA
#pragma unroll 4
        for (int kk = 0; kk < 32; ++kk) {
            float4 av = *(const float4*)&As[kk][ar];
            float4 b0 = *(const float4*)&Bs[kk][br];
            float4 b1 = *(const float4*)&Bs[kk][br + 4];
            float a[4] = {av.x, av.y, av.z, av.w};
            float b[8] = {b0.x,b0.y,b0.z,b0.w,b1.x,b1.y,b1.z,b1.w};
#pragma unroll
            for (int i = 0; i < 4; ++i)
#pragma unroll
                for (int j = 0; j < 8; ++j)
                    acc[i][j] = fmaf(a[i], b[j], acc[i][j]);
        }
        __syncthreads();
    }

    // ---- epilogue ----
    const int row = m0 + ar;
    const int col = n0 + br;
    if (col < N) {     // col%8==0; ldc guarantees col..col+7 in-bounds memory;
                       // cols >= N hold zeros (B staged as 0 there) and are never read
        if (MODE == 2) {
            float* Cz = C + (size_t)z * zstride;
#pragma unroll
            for (int i = 0; i < 4; ++i) {
                float* cr = Cz + (size_t)(row + i) * ldc + col;
                *(float4*)(cr)     = make_float4(acc[i][0],acc[i][1],acc[i][2],acc[i][3]);
                *(float4*)(cr + 4) = make_float4(acc[i][4],acc[i][5],acc[i][6],acc[i][7]);
            }
        } else {
            float4 ga0 = *(const float4*)(gamma + col);
            float4 va0 = *(const float4*)(var + col);
            float4 bi0 = *(const float4*)(bias + col);
            float4 mu0 = *(const float4*)(mean + col);
            float4 be0 = *(const float4*)(beta + col);
            float4 ga1 = *(const float4*)(gamma + col + 4);
            float4 va1 = *(const float4*)(var + col + 4);
            float4 bi1 = *(const float4*)(bias + col + 4);
            float4 mu1 = *(const float4*)(mean + col + 4);
            float4 be1 = *(const float4*)(beta + col + 4);
            float s[8], t8[8];
            s[0]=ga0.x*rsqrtf(va0.x+BN_EPS_F); s[1]=ga0.y*rsqrtf(va0.y+BN_EPS_F);
            s[2]=ga0.z*rsqrtf(va0.z+BN_EPS_F); s[3]=ga0.w*rsqrtf(va0.w+BN_EPS_F);
            s[4]=ga1.x*rsqrtf(va1.x+BN_EPS_F); s[5]=ga1.y*rsqrtf(va1.y+BN_EPS_F);
            s[6]=ga1.z*rsqrtf(va1.z+BN_EPS_F); s[7]=ga1.w*rsqrtf(va1.w+BN_EPS_F);
            t8[0]=fmaf(s[0],bi0.x-mu0.x,be0.x); t8[1]=fmaf(s[1],bi0.y-mu0.y,be0.y);
            t8[2]=fmaf(s[2],bi0.z-mu0.z,be0.z); t8[3]=fmaf(s[3],bi0.w-mu0.w,be0.w);
            t8[4]=fmaf(s[4],bi1.x-mu1.x,be1.x); t8[5]=fmaf(s[5],bi1.y-mu1.y,be1.y);
            t8[6]=fmaf(s[6],bi1.z-mu1.z,be1.z); t8[7]=fmaf(s[7],bi1.w-mu1.w,be1.w);
#pragma unroll
            for (int i = 0; i < 4; ++i) {
                float y[8];
#pragma unroll
                for (int j = 0; j < 8; ++j) {
                    float yy = fmaf(s[j], acc[i][j], t8[j]);
                    if (MODE == 0) yy = fmaxf(yy, 0.f);
                    else           yy = 1.f / (1.f + expf(-yy));
                    y[j] = yy;
                }
                float* cr = C + (size_t)(row + i) * ldc + col;
                *(float4*)(cr)     = make_float4(y[0],y[1],y[2],y[3]);
                *(float4*)(cr + 4) = make_float4(y[4],y[5],y[6],y[7]);
            }
        }
    }
}

// ---------------------------------------------------------------------------
// Split-K=2 reduce for layer 2 + BN + relu. IN-PLACE: h2 overwrites panel z0
// (each thread reads its own index from both panels, then writes it).
// ---------------------------------------------------------------------------
__global__ __launch_bounds__(256)
void reduce2_relu(float* __restrict__ part,     // panel z0; z1 at +2048000
                  const float* __restrict__ bias, const float* __restrict__ gamma,
                  const float* __restrict__ beta, const float* __restrict__ mean,
                  const float* __restrict__ var)
{
    const int i = blockIdx.x * 256 + threadIdx.x;
    if (i >= 2048 * 250) return;
    const int m = i / 250;
    const int n = (i % 250) * 4;
    const size_t off = (size_t)m * 1000 + n;
    float4 a = *(const float4*)(part + off);
    float4 b = *(const float4*)(part + 2048000 + off);
    float4 ga = *(const float4*)(gamma + n);
    float4 va = *(const float4*)(var + n);
    float4 bi = *(const float4*)(bias + n);
    float4 mu = *(const float4*)(mean + n);
    float4 be = *(const float4*)(beta + n);
    float s0 = ga.x*rsqrtf(va.x+BN_EPS_F), s1 = ga.y*rsqrtf(va.y+BN_EPS_F);
    float s2 = ga.z*rsqrtf(va.z+BN_EPS_F), s3 = ga.w*rsqrtf(va.w+BN_EPS_F);
    float4 out;
    out.x = fmaxf(fmaf(s0, a.x + b.x + bi.x - mu.x, be.x), 0.f);
    out.y = fmaxf(fmaf(s1, a.y + b.y + bi.y - mu.y, be.y), 0.f);
    out.z = fmaxf(fmaf(s2, a.z + b.z + bi.z - mu.z, be.z), 0.f);
    out.w = fmaxf(fmaf(s3, a.w + b.w + bi.w - mu.w, be.w), 0.f);
    *(float4*)(part + off) = out;
}

// ---------------------------------------------------------------------------
// Split-K reduce for layer 3 + BN + sigmoid -> p (2048 x 300)
// ---------------------------------------------------------------------------
__global__ __launch_bounds__(256)
void reduce3_sigmoid(const float* __restrict__ part, int nz, size_t pstride,
                     const float* __restrict__ bias, const float* __restrict__ gamma,
                     const float* __restrict__ beta, const float* __restrict__ mean,
                     const float* __restrict__ var, float* __restrict__ p)
{
    const int i = blockIdx.x * 256 + threadIdx.x;
    if (i >= 2048 * 75) return;
    const int m = i / 75;
    const int n = (i % 75) * 4;
    const size_t off = (size_t)m * 304 + n;
    float d0 = 0.f, d1 = 0.f, d2 = 0.f, d3 = 0.f;
    for (int zz = 0; zz < nz; ++zz) {
        float4 v = *(const float4*)(part + zz * pstride + off);
        d0 += v.x; d1 += v.y; d2 += v.z; d3 += v.w;
    }
    float4 ga = *(const float4*)(gamma + n);
    float4 va = *(const float4*)(var + n);
    float4 bi = *(const float4*)(bias + n);
    float4 mu = *(const float4*)(mean + n);
    float4 be = *(const float4*)(beta + n);
    float s0 = ga.x*rsqrtf(va.x+BN_EPS_F), s1 = ga.y*rsqrtf(va.y+BN_EPS_F);
    float s2 = ga.z*rsqrtf(va.z+BN_EPS_F), s3 = ga.w*rsqrtf(va.w+BN_EPS_F);
    float4 out;
    out.x = 1.f/(1.f+expf(-(fmaf(s0, d0 + bi.x - mu.x, be.x))));
    out.y = 1.f/(1.f+expf(-(fmaf(s1, d1 + bi.y - mu.y, be.y))));
    out.z = 1.f/(1.f+expf(-(fmaf(s2, d2 + bi.z - mu.z, be.z))));
    out.w = 1.f/(1.f+expf(-(fmaf(s3, d3 + bi.w - mu.w, be.w))));
    *(float4*)(p + (size_t)m * 300 + n) = out;
}

// ---------------------------------------------------------------------------
// Lorentz spectrum: one block per batch row.
// ---------------------------------------------------------------------------
__global__ __launch_bounds__(320)
void lorentz_kernel(const float* __restrict__ P,     // 2048 x 300
                    const float* __restrict__ G,     // 2048 x 8
                    const float* __restrict__ wgrid, // 300
                    float* __restrict__ T)           // 2048 x 300
{
    __shared__ float s_w02[100], s_wp2[100], s_wp2g[100], s_g2[100];
    const int b   = blockIdx.x;
    const int tid = threadIdx.x;
    if (tid < 100) {
        const float* p = P + (size_t)b*300 + 3*tid;
        const float w0 = p[0]*5.f;
        const float wp = p[1]*5.f;
        const float g  = p[2]*0.5f;
        s_w02[tid]  = w0*w0;
        s_wp2[tid]  = wp*wp;
        s_g2[tid]   = g*g;
        s_wp2g[tid] = wp*wp*g;
    }
    __syncthreads();
    if (tid < 300) {
        const float wg = wgrid[tid];
        const float w2 = wg*wg;
        float e1 = 0.f, e2s = 0.f;
#pragma unroll 10
        for (int l = 0; l < 100; ++l) {
            const float s1    = s_w02[l] - w2;
            const float denom = fmaf(s1, s1, w2 * s_g2[l]);
            const float r     = __builtin_amdgcn_rcpf(denom);
            e1  = fmaf(s_wp2[l]*s1, r, e1);
            e2s = fmaf(s_wp2g[l],   r, e2s);
        }
        e1 += 10.f;
        const float e2  = e2s * wg;
        const float mag = sqrtf(fmaf(e1, e1, e2*e2));
        const float nn  = sqrtf(0.5f*(mag + e1));
        const float kk  = sqrtf(fmaxf(0.5f*(mag - e1), 0.f));
        const float d   = fmaxf(fmaxf(G[b*8+4], G[b*8+5]),
                                fmaxf(G[b*8+6], G[b*8+7]));
        const float ab  = expf(-0.006283185307179586f * d * kk);
        const float np1 = nn + 1.f;
        const float Tv  = 4.f*nn / fmaf(np1, np1, kk*kk) * ab;
        T[(size_t)b*300 + tid] = Tv;
    }
}

extern "C" void kernel_launch(void* const* d_in, const int* in_sizes, int n_in,
                              void* d_out, int out_size, void* d_ws, size_t ws_size,
                              hipStream_t stream) {
    const float* G      = (const float*)d_in[0];
    const float* W1     = (const float*)d_in[1];
    const float* b1     = (const float*)d_in[2];
    const float* gamma1 = (const float*)d_in[3];
    const float* beta1  = (const float*)d_in[4];
    const float* mean1  = (const float*)d_in[5];
    const float* var1   = (const float*)d_in[6];
    const float* W2     = (const float*)d_in[7];
    const float* b2     = (const float*)d_in[8];
    const float* gamma2 = (const float*)d_in[9];
    const float* beta2  = (const float*)d_in[10];
    const float* mean2  = (const float*)d_in[11];
    const float* var2   = (const float*)d_in[12];
    const float* W3     = (const float*)d_in[13];
    const float* b3     = (const float*)d_in[14];
    const float* gamma3 = (const float*)d_in[15];
    const float* beta3  = (const float*)d_in[16];
    const float* mean3  = (const float*)d_in[17];
    const float* var3   = (const float*)d_in[18];
    const float* wgrid  = (const float*)d_in[19];

    float* ws = (float*)d_ws;
    float* T  = (float*)d_out;

    float* h1    = ws;                 // [0 : 2,048,000) floats
    float* part3 = ws;                 // aliases h1 after it's dead: 3 x 622,592
    float* p     = ws + 4096000;       // 614,400 floats

    // Layer 1 (K=8, memory-bound)
    l1_kernel<<<2048, 256, 0, stream>>>(G, W1, b1, gamma1, beta1, mean1, var1, h1);

    // Deterministic path choice on the session-constant ws_size.
    const bool big = ws_size >= (size_t)24576000;   // split-K2 needs 6,144,000 floats

    float* h2;
    if (big) {
        float* part2 = ws + 2048000;   // [2.048M : 6.144M) floats, 2 panels
        h2 = part2;                    // reduce2 writes h2 in-place over panel z0

        // Layer 2: split-K=2 (grid 8n x 32m x 2z = 512 blocks, 8 waves/CU)
        gemm_w<2><<<dim3(8, 32, 2), 256, 0, stream>>>(
            h1, 1000, 1000, W2, 1000, 1000, 512,
            nullptr, nullptr, nullptr, nullptr, nullptr, part2, 1000, 2048000);
        reduce2_relu<<<2000, 256, 0, stream>>>(part2, b2, gamma2, beta2, mean2, var2);
    } else {
        h2 = ws + 2048000;             // [2.048M : 4.096M)
        // Layer 2: single pass, fused BN+relu (grid 8 x 32 = 256 blocks)
        gemm_w<0><<<dim3(8, 32, 1), 256, 0, stream>>>(
            h1, 1000, 1000, W2, 1000, 1000, 1000,
            b2, gamma2, beta2, mean2, var2, h2, 1000, 0);
    }

    // Layer 3: 2048x300, K=1000, split-K=3 (grid 3n x 32m x 3z = 288 blocks)
    // part3 aliases h1 (dead after layer 2). ldc=304 >= 296+8.
    gemm_w<2><<<dim3(3, 32, 3), 256, 0, stream>>>(
        h2, 1000, 1000, W3, 300, 1000, 352,
        nullptr, nullptr, nullptr, nullptr, nullptr, part3, 304, 622592);

    // Reduce partials + BN + sigmoid -> p (p sits above part3's 1.87M floats;
    // in the big path it overwrites dead part2-z1 only after gemm3 finished)
    reduce3_sigmoid<<<600, 256, 0, stream>>>(part3, 3, 622592,
        b3, gamma3, beta3, mean3, var3, p);

    // Lorentz spectrum -> T
    lorentz_kernel<<<2048, 320, 0, stream>>>(p, G, wgrid, T);
}